// Round 1
// baseline (583.365 us; speedup 1.0000x reference)
//
#include <hip/hip_runtime.h>
#include <math.h>

namespace {
constexpr int kB = 4096;
constexpr int kD = 9216;   // 64*12*12
constexpr int kE = 8;
constexpr int kH = 128;
constexpr int kO = 10;
constexpr int PSTR = 32;   // shorts per h1 pixel (64 B stride)
constexpr int KSPLIT = 8;  // expert GEMM k-split: 9216/8 = 1152

typedef __attribute__((ext_vector_type(8))) short short8;   // 8 bf16
typedef __attribute__((ext_vector_type(4))) float f32x4;    // MFMA acc

__device__ inline unsigned f2bf(float f) {  // fp32 -> bf16 bits, RNE
  unsigned u = __float_as_uint(f);
  return (u + 0x7fffu + ((u >> 16) & 1u)) >> 16;
}
__device__ inline float bf2f(unsigned b) { return __uint_as_float(b << 16); }

// h1 LDS slot swizzle (R11): short-offset within a pixel's 32-short region,
// XORed by pixel bits. Reads are ds_read_b128 at pixel*64B + kg*16B; within a
// 16-lane quarter-wave (fixed kg) the 16 pixels are 8 even + 8 odd -> 8 lanes
// share one 16B slot mod 128B with 8 distinct rows = 8-way bank conflict
// (SQ_LDS_BANK_CONFLICT 4.25e7 = ~26% of conv cycles). XOR with (pix>>1)&3
// spreads them 2 lanes/slot (free, m136). Pure layout permutation: stored
// values bit-identical, numerics frozen.
__device__ inline int h1swz(int pix, int shortoff) {
  return pix * PSTR + (shortoff ^ (((pix >> 1) & 3) << 3));
}

// w1 -> MFMA B-frag order, bf16 hi/lo. Layout:
// [e][k>>5][nt][lane][j], lane = ((k>>3)&3)<<4 | (n&15), j = k&7.
// Block 0 additionally packs c2w B-frags and zeroes counts.
__global__ __launch_bounds__(256) void prep_w1(
    const float* __restrict__ w1, ushort* __restrict__ w1ph,
    ushort* __restrict__ w1pl, const float* __restrict__ c2w,
    ushort* __restrict__ Bph, ushort* __restrict__ Bpl,
    int* __restrict__ counts) {
  if (blockIdx.x == 0) {
    if (threadIdx.x < kE) counts[threadIdx.x] = 0;
    for (int i = threadIdx.x; i < 9 * 4 * 64 * 8; i += 256) {
      int j = i & 7, lane = (i >> 3) & 63, nt = (i >> 9) & 3, tap = i >> 11;
      int n = nt * 16 + (lane & 15);
      int c1 = (lane >> 4) * 8 + j;
      float v = c2w[(n * 32 + c1) * 9 + tap];
      unsigned hb = f2bf(v);
      Bph[i] = (ushort)hb;
      Bpl[i] = (ushort)f2bf(v - bf2f(hb));
    }
  }
  int t = blockIdx.x * 256 + threadIdx.x;
  int n = t & 127;
  int rem = t >> 7;
  int k8 = rem % 1152;
  int e = rem / 1152;
  const float* src = w1 + ((size_t)e * kD + (size_t)k8 * 8) * kH + n;
  short8 sh, sl;
#pragma unroll
  for (int j = 0; j < 8; ++j) {
    float v = src[(size_t)j * kH];
    unsigned hb = f2bf(v);
    sh[j] = (short)hb;
    sl[j] = (short)f2bf(v - bf2f(hb));
  }
  size_t base =
      ((((size_t)e * 288 + (k8 >> 2)) * 8 + (n >> 4)) * 64 +
       (((k8 & 3) << 4) | (n & 15))) * 8;
  *(short8*)(w1ph + base) = sh;
  *(short8*)(w1pl + base) = sl;
}

// One 256-thread block per sample. Wave w owns ntile w (16 chans), covers all
// 18 mt tiles: B-frag residency 72 regs/wave (was 144) -> unified VGPR+AGPR
// total ~130-170 -> 3-4 waves/SIMD; LDS caps 3 blocks/CU (R10 post-mortem:
// unified reg file is THE conv occupancy limiter; VGPR_Count hides AGPRs).
// (256,2): min 2 is trivially met; plain bounds let allocator run unbounded
// (R10: 1 block/CU). NUMERICS FROZEN: conv1 loop identical; per output value
// the tap order and Al*Bh -> Ah*Bl -> Ah*Bh chain are identical to R2-R9.
// R11: h1 LDS slot-swizzle (h1swz) on store+load only — bit-identical values.
__global__ __launch_bounds__(256, 2) void conv_kernel(
    const float* __restrict__ x, const float* __restrict__ c1w,
    const float* __restrict__ c1b, const float* __restrict__ b2g,
    const ushort* __restrict__ Bph, const ushort* __restrict__ Bpl,
    float* __restrict__ h) {
  __shared__ float xs[784];
  __shared__ float w1s[288];
  __shared__ float b1s[32];
  __shared__ ushort h1h[364 * PSTR];  // 23.3 KB
  __shared__ ushort h1l[364 * PSTR];
  const int b = blockIdx.x, tid = threadIdx.x;
  const int lane = tid & 63, wave = tid >> 6;  // wave = ntile (16 chans)

  short8 Bh[9], Bl[9];
#pragma unroll
  for (int tap = 0; tap < 9; ++tap) {
    int fi = ((tap * 4 + wave) * 64 + lane) * 8;
    Bh[tap] = *(const short8*)(Bph + fi);
    Bl[tap] = *(const short8*)(Bpl + fi);
  }
  float b2v = b2g[wave * 16 + (lane & 15)];

  const float* xb = x + (size_t)b * 784;
  for (int i = tid; i < 784; i += 256) xs[i] = xb[i];
  for (int i = tid; i < 288; i += 256) w1s[i] = c1w[i];
  if (tid < 32) b1s[tid] = c1b[tid];
  __syncthreads();

  float* hb = h + (size_t)b * kD;
  for (int pass = 0; pass < 2; ++pass) {
    for (int i = tid; i < 364 * 16; i += 256) {
      int p = i >> 4, cp = (i & 15) * 2;
      int r = p / 26, col = p - r * 26;
      const float* xr = xs + (pass * 12 + r) * 28 + col;
      const float* w0 = w1s + cp * 9;
      float v0 = b1s[cp], v1 = b1s[cp + 1];
#pragma unroll
      for (int ky = 0; ky < 3; ++ky)
#pragma unroll
        for (int kx = 0; kx < 3; ++kx) {
          float xv = xr[ky * 28 + kx];
          v0 += xv * w0[ky * 3 + kx];
          v1 += xv * w0[9 + ky * 3 + kx];
        }
      v0 = fmaxf(v0, 0.f);
      v1 = fmaxf(v1, 0.f);
      unsigned h0 = f2bf(v0), h1b = f2bf(v1);
      unsigned l0 = f2bf(v0 - bf2f(h0)), l1 = f2bf(v1 - bf2f(h1b));
      int si = h1swz(p, cp);
      *(unsigned*)&h1h[si] = h0 | (h1b << 16);
      *(unsigned*)&h1l[si] = l0 | (l1 << 16);
    }
    __syncthreads();
    const int m = lane & 15, kg = lane >> 4;
    const int kg8 = kg * 8;
    for (int mt = 0; mt < 18; ++mt) {
      int cell = mt * 4 + (m >> 2), sub = m & 3;
      int cy = cell / 12, cx = cell - cy * 12;
      int yy = 2 * cy + (sub >> 1), xx = 2 * cx + (sub & 1);
      const int p0 = yy * 26 + xx;
      f32x4 acc = {0.f, 0.f, 0.f, 0.f};
#pragma unroll
      for (int ky = 0; ky < 3; ++ky)
#pragma unroll
        for (int kx = 0; kx < 3; ++kx) {
          const int tap = ky * 3 + kx;
          const int off = h1swz(p0 + ky * 26 + kx, kg8);
          short8 Ah = *(const short8*)(h1h + off);  // b128
          short8 Al = *(const short8*)(h1l + off);  // +23296B imm offset
          acc = __builtin_amdgcn_mfma_f32_16x16x32_bf16(Al, Bh[tap], acc, 0, 0, 0);
          acc = __builtin_amdgcn_mfma_f32_16x16x32_bf16(Ah, Bl[tap], acc, 0, 0, 0);
          acc = __builtin_amdgcn_mfma_f32_16x16x32_bf16(Ah, Bh[tap], acc, 0, 0, 0);
        }
      int cellg = mt * 4 + kg;
      int gy = cellg / 12, gx = cellg - gy * 12;
      int orow = (pass * 6 + gy) * 12 + gx;
      float p0v = fmaxf(fmaxf(acc[0], acc[1]), fmaxf(acc[2], acc[3]));
      hb[(wave * 16 + m) * 144 + orow] = fmaxf(p0v + b2v, 0.f);
    }
    __syncthreads();
  }
}

// 4 tokens per 256-thread block; per-wave numerics frozen (R5 verbatim).
__global__ __launch_bounds__(256) void gate_kernel(
    const float* __restrict__ h, const float* __restrict__ gw,
    int* __restrict__ idx, float* __restrict__ scale,
    int* __restrict__ counts) {
  const int b = blockIdx.x * 4 + (threadIdx.x >> 6);
  const int lane = threadIdx.x & 63;
  const float* hb = h + (size_t)b * kD;
  float acc[kE] = {0, 0, 0, 0, 0, 0, 0, 0};
  for (int i = lane; i < kD; i += 64) {
    float hv = hb[i];
    const float* g = gw + (size_t)i * kE;
#pragma unroll
    for (int e = 0; e < kE; ++e) acc[e] += hv * g[e];
  }
#pragma unroll
  for (int off = 32; off > 0; off >>= 1) {
#pragma unroll
    for (int e = 0; e < kE; ++e) acc[e] += __shfl_down(acc[e], off, 64);
  }
  if (lane == 0) {
    float m = acc[0];
    int bi = 0;
#pragma unroll
    for (int e = 1; e < kE; ++e)
      if (acc[e] > m) { m = acc[e]; bi = e; }
    float s = 0.f;
#pragma unroll
    for (int e = 0; e < kE; ++e) s += expf(acc[e] - m);
    idx[b] = bi;
    scale[b] = 1.0f / s;
    atomicAdd(&counts[bi], 1);
  }
}

// Single block: exclusive scan of counts + bucket scatter via LDS cursors.
__global__ __launch_bounds__(256) void scan_scatter(
    const int* __restrict__ counts, const int* __restrict__ idx,
    int* __restrict__ offsets, int* __restrict__ perm) {
  __shared__ int soff[kE + 1];
  __shared__ int cur[kE];
  if (threadIdx.x == 0) {
    int o = 0;
    for (int e = 0; e < kE; ++e) {
      soff[e] = o;
      cur[e] = o;
      o += counts[e];
    }
    soff[kE] = o;
  }
  __syncthreads();
  for (int b = threadIdx.x; b < kB; b += 256) {
    int e = idx[b];
    int pos = atomicAdd(&cur[e], 1);
    perm[pos] = b;
  }
  if (threadIdx.x <= kE) offsets[threadIdx.x] = soff[threadIdx.x];
}

// MFMA expert GEMM. Grid (e=8, ks=8, tile=16). B staged through LDS once per
// block per bk (R9 win). Numerics frozen vs R4-R10.
__global__ __launch_bounds__(256) void expert_gemm(
    const float* __restrict__ h, const ushort* __restrict__ w1ph,
    const ushort* __restrict__ w1pl, const int* __restrict__ perm,
    const int* __restrict__ offsets, float* __restrict__ preact) {
  const int e = blockIdx.x, ks = blockIdx.y;
  const int start = offsets[e] + blockIdx.z * 64;
  const int end = offsets[e + 1];
  if (start >= end) return;
  const int M = min(64, end - start);
  __shared__ ushort Afh[4096];  // A frags [kstep][g][lane][8], 8 KB
  __shared__ ushort Afl[4096];
  __shared__ ushort Bsh[8192];  // B frags [kstep][nt][lane][8], 16 KB
  __shared__ ushort Bsl[8192];
  __shared__ int rows[64];
  const int tid = threadIdx.x;
  if (tid < 64) rows[tid] = perm[start + min(tid, M - 1)];
  __syncthreads();
  const int wave = tid >> 6, lane = tid & 63;
  const int m15 = lane & 15, kg4 = lane >> 4;
  const int srow = tid >> 2, spart = tid & 3;
  const int kbase = ks * (kD / KSPLIT);
  const float* hp0 = h + (size_t)rows[srow] * kD + kbase + spart * 16;
  const int skstep = spart >> 1, skg = (spart & 1) * 2;
  const int sg = srow >> 4, sm = srow & 15;
  ushort* wh0 = &Afh[((skstep * 4 + sg) * 64 + skg * 16 + sm) * 8];
  ushort* wl0 = &Afl[((skstep * 4 + sg) * 64 + skg * 16 + sm) * 8];
  f32x4 acc[8];
#pragma unroll
  for (int j = 0; j < 8; ++j) acc[j] = {0.f, 0.f, 0.f, 0.f};

  for (int bk = 0; bk < kD / KSPLIT; bk += 64) {
    // ---- stage A ----
#pragma unroll
    for (int c = 0; c < 2; ++c) {
      float4 v0 = *(const float4*)(hp0 + bk + c * 8);
      float4 v1 = *(const float4*)(hp0 + bk + c * 8 + 4);
      short8 ph, pl;
      float f[8] = {v0.x, v0.y, v0.z, v0.w, v1.x, v1.y, v1.z, v1.w};
#pragma unroll
      for (int j = 0; j < 8; ++j) {
        unsigned hb = f2bf(f[j]);
        ph[j] = (short)hb;
        pl[j] = (short)f2bf(f[j] - bf2f(hb));
      }
      *(short8*)(wh0 + c * 128) = ph;
      *(short8*)(wl0 + c * 128) = pl;
    }
    // ---- stage B: 2 kg32 blocks x 4096 shorts, contiguous in w1p ----
    {
      const size_t bbase =
          ((size_t)e * 288 + ((kbase + bk) >> 5)) * 4096;
#pragma unroll
      for (int q = 0; q < 4; ++q) {
        int c = tid + q * 256;  // b128 chunk id, 1024 total
        *(short8*)&Bsh[c * 8] = *(const short8*)(w1ph + bbase + (size_t)c * 8);
        *(short8*)&Bsl[c * 8] = *(const short8*)(w1pl + bbase + (size_t)c * 8);
      }
    }
    __syncthreads();
#pragma unroll
    for (int kstep = 0; kstep < 2; ++kstep) {
      const ushort* af = &Afh[((kstep * 4 + wave) * 64 + lane) * 8];
      short8 ah = *(const short8*)af;
      short8 al = *(const short8*)(af + (Afl - Afh));
      const ushort* bph = &Bsh[kstep * 4096 + lane * 8];
      const ushort* bpl = &Bsl[kstep * 4096 + lane * 8];
#pragma unroll
      for (int nt = 0; nt < 8; ++nt) {
        short8 bh = *(const short8*)(bph + nt * 512);
        short8 bl = *(const short8*)(bpl + nt * 512);
        acc[nt] = __builtin_amdgcn_mfma_f32_16x16x32_bf16(al, bh, acc[nt], 0, 0, 0);
        acc[nt] = __builtin_amdgcn_mfma_f32_16x16x32_bf16(ah, bl, acc[nt], 0, 0, 0);
        acc[nt] = __builtin_amdgcn_mfma_f32_16x16x32_bf16(ah, bh, acc[nt], 0, 0, 0);
      }
    }
    __syncthreads();
  }
  float* pb = preact + (size_t)ks * kB * kH;
#pragma unroll
  for (int r = 0; r < 4; ++r) {
    int row = wave * 16 + kg4 * 4 + r;
    if (row < M) {
      float* pr = pb + (size_t)rows[row] * kH + m15;
#pragma unroll
      for (int nt = 0; nt < 8; ++nt) pr[nt * 16] = acc[nt][r];
    }
  }
}

// Per-token tail: sum k-split slices, bias+relu, w2 matmul, scale, log_softmax.
__global__ __launch_bounds__(64) void expert_tail(
    const float* __restrict__ preact, const float* __restrict__ b1,
    const float* __restrict__ w2, const float* __restrict__ b2,
    const int* __restrict__ idx, const float* __restrict__ scale,
    float* __restrict__ out) {
  const int b = blockIdx.x;
  const int lane = threadIdx.x;
  const int e = idx[b];
  float pa = 0.f, pc = 0.f;
#pragma unroll
  for (int ks = 0; ks < KSPLIT; ++ks) {
    const float* ps = preact + ((size_t)ks * kB + b) * kH;
    pa += ps[lane];
    pc += ps[64 + lane];
  }
  float hea = fmaxf(pa + b1[e * kH + lane], 0.f);
  float heb = fmaxf(pc + b1[e * kH + 64 + lane], 0.f);
  const float* w2a = w2 + ((size_t)e * kH + lane) * kO;
  const float* w2b = w2a + 64 * kO;
  float part[kO];
#pragma unroll
  for (int o = 0; o < kO; ++o) part[o] = hea * w2a[o] + heb * w2b[o];
#pragma unroll
  for (int off = 32; off > 0; off >>= 1)
#pragma unroll
    for (int o = 0; o < kO; ++o) part[o] += __shfl_down(part[o], off, 64);
  if (lane == 0) {
    const float sc = scale[b];
    float v[kO], m = -1e30f;
#pragma unroll
    for (int o = 0; o < kO; ++o) {
      v[o] = (part[o] + b2[e * kO + o]) * sc;
      m = fmaxf(m, v[o]);
    }
    float s = 0.f;
#pragma unroll
    for (int o = 0; o < kO; ++o) s += expf(v[o] - m);
    const float lse = m + logf(s);
#pragma unroll
    for (int o = 0; o < kO; ++o) out[(size_t)b * kO + o] = v[o] - lse;
  }
}

}  // namespace

extern "C" void kernel_launch(void* const* d_in, const int* in_sizes, int n_in,
                              void* d_out, int out_size, void* d_ws,
                              size_t ws_size, hipStream_t stream) {
  (void)in_sizes; (void)n_in; (void)out_size; (void)ws_size;
  const float* x   = (const float*)d_in[0];
  const float* c1w = (const float*)d_in[1];
  const float* c1b = (const float*)d_in[2];
  const float* c2w = (const float*)d_in[3];
  const float* c2b = (const float*)d_in[4];
  const float* gw  = (const float*)d_in[5];
  const float* w1  = (const float*)d_in[6];
  const float* b1  = (const float*)d_in[7];
  const float* w2  = (const float*)d_in[8];
  const float* b2  = (const float*)d_in[9];
  float* out = (float*)d_out;

  char* ws = (char*)d_ws;
  float* h = (float*)ws;
  size_t off = (size_t)kB * kD * sizeof(float);                     // 151.0 MB
  ushort* w1ph = (ushort*)(ws + off); off += (size_t)kE * kD * kH * 2;  // 18.9 MB
  ushort* w1pl = (ushort*)(ws + off); off += (size_t)kE * kD * kH * 2;  // 18.9 MB
  float* preact = (float*)(ws + off); off += (size_t)KSPLIT * kB * kH * 4;  // 16.8 MB
  ushort* Bph = (ushort*)(ws + off);  off += 9 * 4 * 64 * 8 * 2;
  ushort* Bpl = (ushort*)(ws + off);  off += 9 * 4 * 64 * 8 * 2;
  int* idx = (int*)(ws + off);        off += (size_t)kB * 4;
  float* scale = (float*)(ws + off);  off += (size_t)kB * 4;
  int* perm = (int*)(ws + off);       off += (size_t)kB * 4;
  int* counts = (int*)(ws + off);     off += 64;
  int* offsets = (int*)(ws + off);    off += 64;

  prep_w1<<<4608, 256, 0, stream>>>(w1, w1ph, w1pl, c2w, Bph, Bpl, counts);
  conv_kernel<<<kB, 256, 0, stream>>>(x, c1w, c1b, c2b, Bph, Bpl, h);
  gate_kernel<<<kB / 4, 256, 0, stream>>>(h, gw, idx, scale, counts);
  scan_scatter<<<1, 256, 0, stream>>>(counts, idx, offsets, perm);
  dim3 eg(kE, KSPLIT, 16);
  expert_gemm<<<eg, 256, 0, stream>>>(h, w1ph, w1pl, perm, offsets, preact);
  expert_tail<<<kB, 64, 0, stream>>>(preact, b1, w2, b2, idx, scale, out);
}

// Round 2
// 566.666 us; speedup vs baseline: 1.0295x; 1.0295x over previous
//
#include <hip/hip_runtime.h>
#include <math.h>

namespace {
constexpr int kB = 4096;
constexpr int kD = 9216;   // 64*12*12
constexpr int kE = 8;
constexpr int kH = 128;
constexpr int kO = 10;
constexpr int PSTR = 32;   // shorts per h1 pixel (64 B stride)
constexpr int KSPLIT = 8;  // expert GEMM k-split: 9216/8 = 1152

typedef __attribute__((ext_vector_type(8))) short short8;   // 8 bf16
typedef __attribute__((ext_vector_type(4))) float f32x4;    // MFMA acc

__device__ inline unsigned f2bf(float f) {  // fp32 -> bf16 bits, RNE
  unsigned u = __float_as_uint(f);
  return (u + 0x7fffu + ((u >> 16) & 1u)) >> 16;
}
__device__ inline float bf2f(unsigned b) { return __uint_as_float(b << 16); }

// w1 -> MFMA B-frag order, bf16 hi/lo. Layout:
// [e][k>>5][nt][lane][j], lane = ((k>>3)&3)<<4 | (n&15), j = k&7.
// Block 0 additionally packs c2w B-frags and zeroes counts.
__global__ __launch_bounds__(256) void prep_w1(
    const float* __restrict__ w1, ushort* __restrict__ w1ph,
    ushort* __restrict__ w1pl, const float* __restrict__ c2w,
    ushort* __restrict__ Bph, ushort* __restrict__ Bpl,
    int* __restrict__ counts) {
  if (blockIdx.x == 0) {
    if (threadIdx.x < kE) counts[threadIdx.x] = 0;
    for (int i = threadIdx.x; i < 9 * 4 * 64 * 8; i += 256) {
      int j = i & 7, lane = (i >> 3) & 63, nt = (i >> 9) & 3, tap = i >> 11;
      int n = nt * 16 + (lane & 15);
      int c1 = (lane >> 4) * 8 + j;
      float v = c2w[(n * 32 + c1) * 9 + tap];
      unsigned hb = f2bf(v);
      Bph[i] = (ushort)hb;
      Bpl[i] = (ushort)f2bf(v - bf2f(hb));
    }
  }
  int t = blockIdx.x * 256 + threadIdx.x;
  int n = t & 127;
  int rem = t >> 7;
  int k8 = rem % 1152;
  int e = rem / 1152;
  const float* src = w1 + ((size_t)e * kD + (size_t)k8 * 8) * kH + n;
  short8 sh, sl;
#pragma unroll
  for (int j = 0; j < 8; ++j) {
    float v = src[(size_t)j * kH];
    unsigned hb = f2bf(v);
    sh[j] = (short)hb;
    sl[j] = (short)f2bf(v - bf2f(hb));
  }
  size_t base =
      ((((size_t)e * 288 + (k8 >> 2)) * 8 + (n >> 4)) * 64 +
       (((k8 & 3) << 4) | (n & 15))) * 8;
  *(short8*)(w1ph + base) = sh;
  *(short8*)(w1pl + base) = sl;
}

// One 256-thread block per sample. Wave w owns ntile w (16 chans), covers all
// mt tiles. R11 post-mortem: LDS bank-conflict counter is invariant to slot
// swizzles and is NOT the bottleneck (~9% of block latency, absorbed by TLP);
// the real signal is MfmaUtil 45 + VALUBusy 45 at Occupancy 31% -> both pipes
// half-idle -> latency-bound at 3 blocks/CU (LDS 51.2 KB was the cap).
// R12: 3 passes x 8 conv2-rows (10 h1 rows) instead of 2 x 12 (14 rows):
// h1h+h1l 46.6->33.3 KB, LDS total 37.9 KB -> 4 blocks/CU (16 waves, +33%).
// Cost: h1 rows {8,9,16,17} conv1-computed twice (+15% of conv1 phase).
// NUMERICS FROZEN: per output value the conv1 expression (absolute row), tap
// order, and Al*Bh -> Ah*Bl -> Ah*Bh chain are identical to R2-R10.
// (256,4): cap unified VGPR+AGPR at 128 so 4 waves/SIMD is reachable (R0 ran
// 84 arch-VGPR; acc is one f32x4 + 72 B-frag regs -> fits).
__global__ __launch_bounds__(256, 4) void conv_kernel(
    const float* __restrict__ x, const float* __restrict__ c1w,
    const float* __restrict__ c1b, const float* __restrict__ b2g,
    const ushort* __restrict__ Bph, const ushort* __restrict__ Bpl,
    float* __restrict__ h) {
  __shared__ float xs[784];
  __shared__ float w1s[288];
  __shared__ float b1s[32];
  __shared__ ushort h1h[260 * PSTR];  // 16.25 KB
  __shared__ ushort h1l[260 * PSTR];
  const int b = blockIdx.x, tid = threadIdx.x;
  const int lane = tid & 63, wave = tid >> 6;  // wave = ntile (16 chans)

  short8 Bh[9], Bl[9];
#pragma unroll
  for (int tap = 0; tap < 9; ++tap) {
    int fi = ((tap * 4 + wave) * 64 + lane) * 8;
    Bh[tap] = *(const short8*)(Bph + fi);
    Bl[tap] = *(const short8*)(Bpl + fi);
  }
  float b2v = b2g[wave * 16 + (lane & 15)];

  const float* xb = x + (size_t)b * 784;
  for (int i = tid; i < 784; i += 256) xs[i] = xb[i];
  for (int i = tid; i < 288; i += 256) w1s[i] = c1w[i];
  if (tid < 32) b1s[tid] = c1b[tid];
  __syncthreads();

  float* hb = h + (size_t)b * kD;
  for (int pass = 0; pass < 3; ++pass) {
    // conv1 into h1 rows [8*pass, 8*pass+9], stored at local rows 0..9.
    for (int i = tid; i < 260 * 16; i += 256) {
      int p = i >> 4, cp = (i & 15) * 2;
      int r = p / 26, col = p - r * 26;
      const float* xr = xs + (pass * 8 + r) * 28 + col;
      const float* w0 = w1s + cp * 9;
      float v0 = b1s[cp], v1 = b1s[cp + 1];
#pragma unroll
      for (int ky = 0; ky < 3; ++ky)
#pragma unroll
        for (int kx = 0; kx < 3; ++kx) {
          float xv = xr[ky * 28 + kx];
          v0 += xv * w0[ky * 3 + kx];
          v1 += xv * w0[9 + ky * 3 + kx];
        }
      v0 = fmaxf(v0, 0.f);
      v1 = fmaxf(v1, 0.f);
      unsigned h0 = f2bf(v0), h1b = f2bf(v1);
      unsigned l0 = f2bf(v0 - bf2f(h0)), l1 = f2bf(v1 - bf2f(h1b));
      *(unsigned*)&h1h[p * PSTR + cp] = h0 | (h1b << 16);
      *(unsigned*)&h1l[p * PSTR + cp] = l0 | (l1 << 16);
    }
    __syncthreads();
    // conv2 (MFMA) + pool for pool rows [4*pass, 4*pass+3].
    const int m = lane & 15, kg = lane >> 4;
    for (int mt = 0; mt < 12; ++mt) {
      int cell = mt * 4 + (m >> 2), sub = m & 3;
      int cy = cell / 12, cx = cell - cy * 12;          // cy local 0..3
      int yy = 2 * cy + (sub >> 1), xx = 2 * cx + (sub & 1);  // local rows 0..7
      const ushort* ah = h1h + (yy * 26 + xx) * PSTR + kg * 8;
      const ushort* al = h1l + (yy * 26 + xx) * PSTR + kg * 8;
      f32x4 acc = {0.f, 0.f, 0.f, 0.f};
#pragma unroll
      for (int ky = 0; ky < 3; ++ky)
#pragma unroll
        for (int kx = 0; kx < 3; ++kx) {
          const int tap = ky * 3 + kx;
          short8 Ah = *(const short8*)(ah + (ky * 26 + kx) * PSTR);  // b128
          short8 Al = *(const short8*)(al + (ky * 26 + kx) * PSTR);
          acc = __builtin_amdgcn_mfma_f32_16x16x32_bf16(Al, Bh[tap], acc, 0, 0, 0);
          acc = __builtin_amdgcn_mfma_f32_16x16x32_bf16(Ah, Bl[tap], acc, 0, 0, 0);
          acc = __builtin_amdgcn_mfma_f32_16x16x32_bf16(Ah, Bh[tap], acc, 0, 0, 0);
        }
      int cellg = mt * 4 + kg;
      int gy = cellg / 12, gx = cellg - gy * 12;        // gy local 0..3
      int orow = (pass * 4 + gy) * 12 + gx;
      float p0 = fmaxf(fmaxf(acc[0], acc[1]), fmaxf(acc[2], acc[3]));
      hb[(wave * 16 + m) * 144 + orow] = fmaxf(p0 + b2v, 0.f);
    }
    __syncthreads();
  }
}

// 4 tokens per 256-thread block; per-wave numerics frozen (R5 verbatim).
__global__ __launch_bounds__(256) void gate_kernel(
    const float* __restrict__ h, const float* __restrict__ gw,
    int* __restrict__ idx, float* __restrict__ scale,
    int* __restrict__ counts) {
  const int b = blockIdx.x * 4 + (threadIdx.x >> 6);
  const int lane = threadIdx.x & 63;
  const float* hb = h + (size_t)b * kD;
  float acc[kE] = {0, 0, 0, 0, 0, 0, 0, 0};
  for (int i = lane; i < kD; i += 64) {
    float hv = hb[i];
    const float* g = gw + (size_t)i * kE;
#pragma unroll
    for (int e = 0; e < kE; ++e) acc[e] += hv * g[e];
  }
#pragma unroll
  for (int off = 32; off > 0; off >>= 1) {
#pragma unroll
    for (int e = 0; e < kE; ++e) acc[e] += __shfl_down(acc[e], off, 64);
  }
  if (lane == 0) {
    float m = acc[0];
    int bi = 0;
#pragma unroll
    for (int e = 1; e < kE; ++e)
      if (acc[e] > m) { m = acc[e]; bi = e; }
    float s = 0.f;
#pragma unroll
    for (int e = 0; e < kE; ++e) s += expf(acc[e] - m);
    idx[b] = bi;
    scale[b] = 1.0f / s;
    atomicAdd(&counts[bi], 1);
  }
}

// Single block: exclusive scan of counts + bucket scatter via LDS cursors.
__global__ __launch_bounds__(256) void scan_scatter(
    const int* __restrict__ counts, const int* __restrict__ idx,
    int* __restrict__ offsets, int* __restrict__ perm) {
  __shared__ int soff[kE + 1];
  __shared__ int cur[kE];
  if (threadIdx.x == 0) {
    int o = 0;
    for (int e = 0; e < kE; ++e) {
      soff[e] = o;
      cur[e] = o;
      o += counts[e];
    }
    soff[kE] = o;
  }
  __syncthreads();
  for (int b = threadIdx.x; b < kB; b += 256) {
    int e = idx[b];
    int pos = atomicAdd(&cur[e], 1);
    perm[pos] = b;
  }
  if (threadIdx.x <= kE) offsets[threadIdx.x] = soff[threadIdx.x];
}

// MFMA expert GEMM. Grid (e=8, ks=8, tile=16). B staged through LDS once per
// block per bk (R9 win). Numerics frozen vs R4-R10.
__global__ __launch_bounds__(256) void expert_gemm(
    const float* __restrict__ h, const ushort* __restrict__ w1ph,
    const ushort* __restrict__ w1pl, const int* __restrict__ perm,
    const int* __restrict__ offsets, float* __restrict__ preact) {
  const int e = blockIdx.x, ks = blockIdx.y;
  const int start = offsets[e] + blockIdx.z * 64;
  const int end = offsets[e + 1];
  if (start >= end) return;
  const int M = min(64, end - start);
  __shared__ ushort Afh[4096];  // A frags [kstep][g][lane][8], 8 KB
  __shared__ ushort Afl[4096];
  __shared__ ushort Bsh[8192];  // B frags [kstep][nt][lane][8], 16 KB
  __shared__ ushort Bsl[8192];
  __shared__ int rows[64];
  const int tid = threadIdx.x;
  if (tid < 64) rows[tid] = perm[start + min(tid, M - 1)];
  __syncthreads();
  const int wave = tid >> 6, lane = tid & 63;
  const int m15 = lane & 15, kg4 = lane >> 4;
  const int srow = tid >> 2, spart = tid & 3;
  const int kbase = ks * (kD / KSPLIT);
  const float* hp0 = h + (size_t)rows[srow] * kD + kbase + spart * 16;
  const int skstep = spart >> 1, skg = (spart & 1) * 2;
  const int sg = srow >> 4, sm = srow & 15;
  ushort* wh0 = &Afh[((skstep * 4 + sg) * 64 + skg * 16 + sm) * 8];
  ushort* wl0 = &Afl[((skstep * 4 + sg) * 64 + skg * 16 + sm) * 8];
  f32x4 acc[8];
#pragma unroll
  for (int j = 0; j < 8; ++j) acc[j] = {0.f, 0.f, 0.f, 0.f};

  for (int bk = 0; bk < kD / KSPLIT; bk += 64) {
    // ---- stage A ----
#pragma unroll
    for (int c = 0; c < 2; ++c) {
      float4 v0 = *(const float4*)(hp0 + bk + c * 8);
      float4 v1 = *(const float4*)(hp0 + bk + c * 8 + 4);
      short8 ph, pl;
      float f[8] = {v0.x, v0.y, v0.z, v0.w, v1.x, v1.y, v1.z, v1.w};
#pragma unroll
      for (int j = 0; j < 8; ++j) {
        unsigned hb = f2bf(f[j]);
        ph[j] = (short)hb;
        pl[j] = (short)f2bf(f[j] - bf2f(hb));
      }
      *(short8*)(wh0 + c * 128) = ph;
      *(short8*)(wl0 + c * 128) = pl;
    }
    // ---- stage B: 2 kg32 blocks x 4096 shorts, contiguous in w1p ----
    {
      const size_t bbase =
          ((size_t)e * 288 + ((kbase + bk) >> 5)) * 4096;
#pragma unroll
      for (int q = 0; q < 4; ++q) {
        int c = tid + q * 256;  // b128 chunk id, 1024 total
        *(short8*)&Bsh[c * 8] = *(const short8*)(w1ph + bbase + (size_t)c * 8);
        *(short8*)&Bsl[c * 8] = *(const short8*)(w1pl + bbase + (size_t)c * 8);
      }
    }
    __syncthreads();
#pragma unroll
    for (int kstep = 0; kstep < 2; ++kstep) {
      const ushort* af = &Afh[((kstep * 4 + wave) * 64 + lane) * 8];
      short8 ah = *(const short8*)af;
      short8 al = *(const short8*)(af + (Afl - Afh));
      const ushort* bph = &Bsh[kstep * 4096 + lane * 8];
      const ushort* bpl = &Bsl[kstep * 4096 + lane * 8];
#pragma unroll
      for (int nt = 0; nt < 8; ++nt) {
        short8 bh = *(const short8*)(bph + nt * 512);
        short8 bl = *(const short8*)(bpl + nt * 512);
        acc[nt] = __builtin_amdgcn_mfma_f32_16x16x32_bf16(al, bh, acc[nt], 0, 0, 0);
        acc[nt] = __builtin_amdgcn_mfma_f32_16x16x32_bf16(ah, bl, acc[nt], 0, 0, 0);
        acc[nt] = __builtin_amdgcn_mfma_f32_16x16x32_bf16(ah, bh, acc[nt], 0, 0, 0);
      }
    }
    __syncthreads();
  }
  float* pb = preact + (size_t)ks * kB * kH;
#pragma unroll
  for (int r = 0; r < 4; ++r) {
    int row = wave * 16 + kg4 * 4 + r;
    if (row < M) {
      float* pr = pb + (size_t)rows[row] * kH + m15;
#pragma unroll
      for (int nt = 0; nt < 8; ++nt) pr[nt * 16] = acc[nt][r];
    }
  }
}

// Per-token tail: sum k-split slices, bias+relu, w2 matmul, scale, log_softmax.
__global__ __launch_bounds__(64) void expert_tail(
    const float* __restrict__ preact, const float* __restrict__ b1,
    const float* __restrict__ w2, const float* __restrict__ b2,
    const int* __restrict__ idx, const float* __restrict__ scale,
    float* __restrict__ out) {
  const int b = blockIdx.x;
  const int lane = threadIdx.x;
  const int e = idx[b];
  float pa = 0.f, pc = 0.f;
#pragma unroll
  for (int ks = 0; ks < KSPLIT; ++ks) {
    const float* ps = preact + ((size_t)ks * kB + b) * kH;
    pa += ps[lane];
    pc += ps[64 + lane];
  }
  float hea = fmaxf(pa + b1[e * kH + lane], 0.f);
  float heb = fmaxf(pc + b1[e * kH + 64 + lane], 0.f);
  const float* w2a = w2 + ((size_t)e * kH + lane) * kO;
  const float* w2b = w2a + 64 * kO;
  float part[kO];
#pragma unroll
  for (int o = 0; o < kO; ++o) part[o] = hea * w2a[o] + heb * w2b[o];
#pragma unroll
  for (int off = 32; off > 0; off >>= 1)
#pragma unroll
    for (int o = 0; o < kO; ++o) part[o] += __shfl_down(part[o], off, 64);
  if (lane == 0) {
    const float sc = scale[b];
    float v[kO], m = -1e30f;
#pragma unroll
    for (int o = 0; o < kO; ++o) {
      v[o] = (part[o] + b2[e * kO + o]) * sc;
      m = fmaxf(m, v[o]);
    }
    float s = 0.f;
#pragma unroll
    for (int o = 0; o < kO; ++o) s += expf(v[o] - m);
    const float lse = m + logf(s);
#pragma unroll
    for (int o = 0; o < kO; ++o) out[(size_t)b * kO + o] = v[o] - lse;
  }
}

}  // namespace

extern "C" void kernel_launch(void* const* d_in, const int* in_sizes, int n_in,
                              void* d_out, int out_size, void* d_ws,
                              size_t ws_size, hipStream_t stream) {
  (void)in_sizes; (void)n_in; (void)out_size; (void)ws_size;
  const float* x   = (const float*)d_in[0];
  const float* c1w = (const float*)d_in[1];
  const float* c1b = (const float*)d_in[2];
  const float* c2w = (const float*)d_in[3];
  const float* c2b = (const float*)d_in[4];
  const float* gw  = (const float*)d_in[5];
  const float* w1  = (const float*)d_in[6];
  const float* b1  = (const float*)d_in[7];
  const float* w2  = (const float*)d_in[8];
  const float* b2  = (const float*)d_in[9];
  float* out = (float*)d_out;

  char* ws = (char*)d_ws;
  float* h = (float*)ws;
  size_t off = (size_t)kB * kD * sizeof(float);                     // 151.0 MB
  ushort* w1ph = (ushort*)(ws + off); off += (size_t)kE * kD * kH * 2;  // 18.9 MB
  ushort* w1pl = (ushort*)(ws + off); off += (size_t)kE * kD * kH * 2;  // 18.9 MB
  float* preact = (float*)(ws + off); off += (size_t)KSPLIT * kB * kH * 4;  // 16.8 MB
  ushort* Bph = (ushort*)(ws + off);  off += 9 * 4 * 64 * 8 * 2;
  ushort* Bpl = (ushort*)(ws + off);  off += 9 * 4 * 64 * 8 * 2;
  int* idx = (int*)(ws + off);        off += (size_t)kB * 4;
  float* scale = (float*)(ws + off);  off += (size_t)kB * 4;
  int* perm = (int*)(ws + off);       off += (size_t)kB * 4;
  int* counts = (int*)(ws + off);     off += 64;
  int* offsets = (int*)(ws + off);    off += 64;

  prep_w1<<<4608, 256, 0, stream>>>(w1, w1ph, w1pl, c2w, Bph, Bpl, counts);
  conv_kernel<<<kB, 256, 0, stream>>>(x, c1w, c1b, c2b, Bph, Bpl, h);
  gate_kernel<<<kB / 4, 256, 0, stream>>>(h, gw, idx, scale, counts);
  scan_scatter<<<1, 256, 0, stream>>>(counts, idx, offsets, perm);
  dim3 eg(kE, KSPLIT, 16);
  expert_gemm<<<eg, 256, 0, stream>>>(h, w1ph, w1pl, perm, offsets, preact);
  expert_tail<<<kB, 64, 0, stream>>>(preact, b1, w2, b2, idx, scale, out);
}

// Round 3
// 565.160 us; speedup vs baseline: 1.0322x; 1.0027x over previous
//
#include <hip/hip_runtime.h>
#include <math.h>

namespace {
constexpr int kB = 4096;
constexpr int kD = 9216;   // 64*12*12
constexpr int kE = 8;
constexpr int kH = 128;
constexpr int kO = 10;
constexpr int PSTR = 32;   // shorts per h1 pixel (64 B stride)
constexpr int KSPLIT = 8;  // expert GEMM k-split: 9216/8 = 1152

typedef __attribute__((ext_vector_type(8))) short short8;   // 8 bf16
typedef __attribute__((ext_vector_type(4))) float f32x4;    // MFMA acc

__device__ inline unsigned f2bf(float f) {  // fp32 -> bf16 bits, RNE
  unsigned u = __float_as_uint(f);
  return (u + 0x7fffu + ((u >> 16) & 1u)) >> 16;
}
__device__ inline float bf2f(unsigned b) { return __uint_as_float(b << 16); }

// w1 -> MFMA B-frag order, bf16 hi/lo. Layout:
// [e][k>>5][nt][lane][j], lane = ((k>>3)&3)<<4 | (n&15), j = k&7.
// Block 0 additionally packs c2w B-frags and zeroes counts.
__global__ __launch_bounds__(256) void prep_w1(
    const float* __restrict__ w1, ushort* __restrict__ w1ph,
    ushort* __restrict__ w1pl, const float* __restrict__ c2w,
    ushort* __restrict__ Bph, ushort* __restrict__ Bpl,
    int* __restrict__ counts) {
  if (blockIdx.x == 0) {
    if (threadIdx.x < kE) counts[threadIdx.x] = 0;
    for (int i = threadIdx.x; i < 9 * 4 * 64 * 8; i += 256) {
      int j = i & 7, lane = (i >> 3) & 63, nt = (i >> 9) & 3, tap = i >> 11;
      int n = nt * 16 + (lane & 15);
      int c1 = (lane >> 4) * 8 + j;
      float v = c2w[(n * 32 + c1) * 9 + tap];
      unsigned hb = f2bf(v);
      Bph[i] = (ushort)hb;
      Bpl[i] = (ushort)f2bf(v - bf2f(hb));
    }
  }
  int t = blockIdx.x * 256 + threadIdx.x;
  int n = t & 127;
  int rem = t >> 7;
  int k8 = rem % 1152;
  int e = rem / 1152;
  const float* src = w1 + ((size_t)e * kD + (size_t)k8 * 8) * kH + n;
  short8 sh, sl;
#pragma unroll
  for (int j = 0; j < 8; ++j) {
    float v = src[(size_t)j * kH];
    unsigned hb = f2bf(v);
    sh[j] = (short)hb;
    sl[j] = (short)f2bf(v - bf2f(hb));
  }
  size_t base =
      ((((size_t)e * 288 + (k8 >> 2)) * 8 + (n >> 4)) * 64 +
       (((k8 & 3) << 4) | (n & 15))) * 8;
  *(short8*)(w1ph + base) = sh;
  *(short8*)(w1pl + base) = sl;
}

// One 256-thread block per sample, R0 2-pass structure (R12's 3-pass reverted:
// +15% conv1 work + partial-line write churn made it slower; occupancy was
// NOT the binding resource). R13: the binding resource is the LDS read pipe:
// 2592 ds_read_b128/block (332k cy/CU ideal + 166k conflict cy = ~79% busy),
// and all 4 waves read IDENTICAL A addresses (address is wave-independent).
// Fix: wave owns an ntile PAIR (32 chans, B-frags 144 regs, loaded once) and
// HALF the mt range (9 mt) -> each A read feeds 2 MFMA chains -> A-traffic
// halved (1296 ds_read/block). MFMA count unchanged. VGPR ~220 -> 2 waves/EU
// ((256,2)); R12 proved extra waves don't help, saturated pipe does.
// NUMERICS FROZEN: per output value the conv1 expression, tap order (ky-major)
// and Al*Bh -> Ah*Bl -> Ah*Bh chain are bit-identical to R0. acc chunked 3 mt
// at a time, all loops fully unrolled (static indexing only).
__global__ __launch_bounds__(256, 2) void conv_kernel(
    const float* __restrict__ x, const float* __restrict__ c1w,
    const float* __restrict__ c1b, const float* __restrict__ b2g,
    const ushort* __restrict__ Bph, const ushort* __restrict__ Bpl,
    float* __restrict__ h) {
  __shared__ float xs[784];
  __shared__ float w1s[288];
  __shared__ float b1s[32];
  __shared__ ushort h1h[364 * PSTR];  // 23.3 KB
  __shared__ ushort h1l[364 * PSTR];
  const int b = blockIdx.x, tid = threadIdx.x;
  const int lane = tid & 63, wave = tid >> 6;
  const int n0 = (wave & 1) * 2;    // ntile pair: {n0, n0+1}
  const int mtb = (wave >> 1) * 9;  // mt range: [mtb, mtb+9)
  const int m = lane & 15, kg = lane >> 4;

  short8 Bh[2][9], Bl[2][9];  // 36 frags = 144 VGPR, resident whole kernel
#pragma unroll
  for (int nt = 0; nt < 2; ++nt)
#pragma unroll
    for (int tap = 0; tap < 9; ++tap) {
      int fi = ((tap * 4 + n0 + nt) * 64 + lane) * 8;
      Bh[nt][tap] = *(const short8*)(Bph + fi);
      Bl[nt][tap] = *(const short8*)(Bpl + fi);
    }
  float b2v[2];
  b2v[0] = b2g[n0 * 16 + m];
  b2v[1] = b2g[(n0 + 1) * 16 + m];

  const float* xb = x + (size_t)b * 784;
  for (int i = tid; i < 784; i += 256) xs[i] = xb[i];
  for (int i = tid; i < 288; i += 256) w1s[i] = c1w[i];
  if (tid < 32) b1s[tid] = c1b[tid];
  __syncthreads();

  float* hb = h + (size_t)b * kD;
  for (int pass = 0; pass < 2; ++pass) {
    // conv1 (R0 verbatim)
    for (int i = tid; i < 364 * 16; i += 256) {
      int p = i >> 4, cp = (i & 15) * 2;
      int r = p / 26, col = p - r * 26;
      const float* xr = xs + (pass * 12 + r) * 28 + col;
      const float* w0 = w1s + cp * 9;
      float v0 = b1s[cp], v1 = b1s[cp + 1];
#pragma unroll
      for (int ky = 0; ky < 3; ++ky)
#pragma unroll
        for (int kx = 0; kx < 3; ++kx) {
          float xv = xr[ky * 28 + kx];
          v0 += xv * w0[ky * 3 + kx];
          v1 += xv * w0[9 + ky * 3 + kx];
        }
      v0 = fmaxf(v0, 0.f);
      v1 = fmaxf(v1, 0.f);
      unsigned h0 = f2bf(v0), h1b = f2bf(v1);
      unsigned l0 = f2bf(v0 - bf2f(h0)), l1 = f2bf(v1 - bf2f(h1b));
      *(unsigned*)&h1h[p * PSTR + cp] = h0 | (h1b << 16);
      *(unsigned*)&h1l[p * PSTR + cp] = l0 | (l1 << 16);
    }
    __syncthreads();
    // conv2 MFMA + pool: 9 mt in 3 chunks of 3, 2 ntiles per A read.
#pragma unroll
    for (int c = 0; c < 3; ++c) {
      f32x4 acc[3][2];
#pragma unroll
      for (int i = 0; i < 3; ++i) {
        acc[i][0] = {0.f, 0.f, 0.f, 0.f};
        acc[i][1] = {0.f, 0.f, 0.f, 0.f};
      }
      int pbase[3];
#pragma unroll
      for (int i = 0; i < 3; ++i) {
        int mt = mtb + c * 3 + i;
        int cell = mt * 4 + (m >> 2), sub = m & 3;
        int cy = cell / 12, cx = cell - cy * 12;
        int yy = 2 * cy + (sub >> 1), xx = 2 * cx + (sub & 1);
        pbase[i] = (yy * 26 + xx) * PSTR + kg * 8;
      }
#pragma unroll
      for (int ky = 0; ky < 3; ++ky)
#pragma unroll
        for (int kx = 0; kx < 3; ++kx) {
          const int tap = ky * 3 + kx;
          const int toff = (ky * 26 + kx) * PSTR;
#pragma unroll
          for (int i = 0; i < 3; ++i) {
            short8 Ah = *(const short8*)(h1h + pbase[i] + toff);  // b128
            short8 Al = *(const short8*)(h1l + pbase[i] + toff);
            acc[i][0] = __builtin_amdgcn_mfma_f32_16x16x32_bf16(Al, Bh[0][tap], acc[i][0], 0, 0, 0);
            acc[i][0] = __builtin_amdgcn_mfma_f32_16x16x32_bf16(Ah, Bl[0][tap], acc[i][0], 0, 0, 0);
            acc[i][0] = __builtin_amdgcn_mfma_f32_16x16x32_bf16(Ah, Bh[0][tap], acc[i][0], 0, 0, 0);
            acc[i][1] = __builtin_amdgcn_mfma_f32_16x16x32_bf16(Al, Bh[1][tap], acc[i][1], 0, 0, 0);
            acc[i][1] = __builtin_amdgcn_mfma_f32_16x16x32_bf16(Ah, Bl[1][tap], acc[i][1], 0, 0, 0);
            acc[i][1] = __builtin_amdgcn_mfma_f32_16x16x32_bf16(Ah, Bh[1][tap], acc[i][1], 0, 0, 0);
          }
        }
#pragma unroll
      for (int i = 0; i < 3; ++i) {
        int mt = mtb + c * 3 + i;
        int cellg = mt * 4 + kg;
        int gy = cellg / 12, gx = cellg - gy * 12;
        int orow = (pass * 6 + gy) * 12 + gx;
#pragma unroll
        for (int nt = 0; nt < 2; ++nt) {
          float p0 = fmaxf(fmaxf(acc[i][nt][0], acc[i][nt][1]),
                           fmaxf(acc[i][nt][2], acc[i][nt][3]));
          hb[((n0 + nt) * 16 + m) * 144 + orow] = fmaxf(p0 + b2v[nt], 0.f);
        }
      }
    }
    __syncthreads();
  }
}

// 4 tokens per 256-thread block; per-wave numerics frozen (R5 verbatim).
__global__ __launch_bounds__(256) void gate_kernel(
    const float* __restrict__ h, const float* __restrict__ gw,
    int* __restrict__ idx, float* __restrict__ scale,
    int* __restrict__ counts) {
  const int b = blockIdx.x * 4 + (threadIdx.x >> 6);
  const int lane = threadIdx.x & 63;
  const float* hb = h + (size_t)b * kD;
  float acc[kE] = {0, 0, 0, 0, 0, 0, 0, 0};
  for (int i = lane; i < kD; i += 64) {
    float hv = hb[i];
    const float* g = gw + (size_t)i * kE;
#pragma unroll
    for (int e = 0; e < kE; ++e) acc[e] += hv * g[e];
  }
#pragma unroll
  for (int off = 32; off > 0; off >>= 1) {
#pragma unroll
    for (int e = 0; e < kE; ++e) acc[e] += __shfl_down(acc[e], off, 64);
  }
  if (lane == 0) {
    float m = acc[0];
    int bi = 0;
#pragma unroll
    for (int e = 1; e < kE; ++e)
      if (acc[e] > m) { m = acc[e]; bi = e; }
    float s = 0.f;
#pragma unroll
    for (int e = 0; e < kE; ++e) s += expf(acc[e] - m);
    idx[b] = bi;
    scale[b] = 1.0f / s;
    atomicAdd(&counts[bi], 1);
  }
}

// Single block: exclusive scan of counts + bucket scatter via LDS cursors.
__global__ __launch_bounds__(256) void scan_scatter(
    const int* __restrict__ counts, const int* __restrict__ idx,
    int* __restrict__ offsets, int* __restrict__ perm) {
  __shared__ int soff[kE + 1];
  __shared__ int cur[kE];
  if (threadIdx.x == 0) {
    int o = 0;
    for (int e = 0; e < kE; ++e) {
      soff[e] = o;
      cur[e] = o;
      o += counts[e];
    }
    soff[kE] = o;
  }
  __syncthreads();
  for (int b = threadIdx.x; b < kB; b += 256) {
    int e = idx[b];
    int pos = atomicAdd(&cur[e], 1);
    perm[pos] = b;
  }
  if (threadIdx.x <= kE) offsets[threadIdx.x] = soff[threadIdx.x];
}

// MFMA expert GEMM. Grid (e=8, ks=8, tile=16). B staged through LDS once per
// block per bk (R9 win). Numerics frozen vs R4-R10.
__global__ __launch_bounds__(256) void expert_gemm(
    const float* __restrict__ h, const ushort* __restrict__ w1ph,
    const ushort* __restrict__ w1pl, const int* __restrict__ perm,
    const int* __restrict__ offsets, float* __restrict__ preact) {
  const int e = blockIdx.x, ks = blockIdx.y;
  const int start = offsets[e] + blockIdx.z * 64;
  const int end = offsets[e + 1];
  if (start >= end) return;
  const int M = min(64, end - start);
  __shared__ ushort Afh[4096];  // A frags [kstep][g][lane][8], 8 KB
  __shared__ ushort Afl[4096];
  __shared__ ushort Bsh[8192];  // B frags [kstep][nt][lane][8], 16 KB
  __shared__ ushort Bsl[8192];
  __shared__ int rows[64];
  const int tid = threadIdx.x;
  if (tid < 64) rows[tid] = perm[start + min(tid, M - 1)];
  __syncthreads();
  const int wave = tid >> 6, lane = tid & 63;
  const int m15 = lane & 15, kg4 = lane >> 4;
  const int srow = tid >> 2, spart = tid & 3;
  const int kbase = ks * (kD / KSPLIT);
  const float* hp0 = h + (size_t)rows[srow] * kD + kbase + spart * 16;
  const int skstep = spart >> 1, skg = (spart & 1) * 2;
  const int sg = srow >> 4, sm = srow & 15;
  ushort* wh0 = &Afh[((skstep * 4 + sg) * 64 + skg * 16 + sm) * 8];
  ushort* wl0 = &Afl[((skstep * 4 + sg) * 64 + skg * 16 + sm) * 8];
  f32x4 acc[8];
#pragma unroll
  for (int j = 0; j < 8; ++j) acc[j] = {0.f, 0.f, 0.f, 0.f};

  for (int bk = 0; bk < kD / KSPLIT; bk += 64) {
    // ---- stage A ----
#pragma unroll
    for (int c = 0; c < 2; ++c) {
      float4 v0 = *(const float4*)(hp0 + bk + c * 8);
      float4 v1 = *(const float4*)(hp0 + bk + c * 8 + 4);
      short8 ph, pl;
      float f[8] = {v0.x, v0.y, v0.z, v0.w, v1.x, v1.y, v1.z, v1.w};
#pragma unroll
      for (int j = 0; j < 8; ++j) {
        unsigned hb = f2bf(f[j]);
        ph[j] = (short)hb;
        pl[j] = (short)f2bf(f[j] - bf2f(hb));
      }
      *(short8*)(wh0 + c * 128) = ph;
      *(short8*)(wl0 + c * 128) = pl;
    }
    // ---- stage B: 2 kg32 blocks x 4096 shorts, contiguous in w1p ----
    {
      const size_t bbase =
          ((size_t)e * 288 + ((kbase + bk) >> 5)) * 4096;
#pragma unroll
      for (int q = 0; q < 4; ++q) {
        int c = tid + q * 256;  // b128 chunk id, 1024 total
        *(short8*)&Bsh[c * 8] = *(const short8*)(w1ph + bbase + (size_t)c * 8);
        *(short8*)&Bsl[c * 8] = *(const short8*)(w1pl + bbase + (size_t)c * 8);
      }
    }
    __syncthreads();
#pragma unroll
    for (int kstep = 0; kstep < 2; ++kstep) {
      const ushort* af = &Afh[((kstep * 4 + wave) * 64 + lane) * 8];
      short8 ah = *(const short8*)af;
      short8 al = *(const short8*)(af + (Afl - Afh));
      const ushort* bph = &Bsh[kstep * 4096 + lane * 8];
      const ushort* bpl = &Bsl[kstep * 4096 + lane * 8];
#pragma unroll
      for (int nt = 0; nt < 8; ++nt) {
        short8 bh = *(const short8*)(bph + nt * 512);
        short8 bl = *(const short8*)(bpl + nt * 512);
        acc[nt] = __builtin_amdgcn_mfma_f32_16x16x32_bf16(al, bh, acc[nt], 0, 0, 0);
        acc[nt] = __builtin_amdgcn_mfma_f32_16x16x32_bf16(ah, bl, acc[nt], 0, 0, 0);
        acc[nt] = __builtin_amdgcn_mfma_f32_16x16x32_bf16(ah, bh, acc[nt], 0, 0, 0);
      }
    }
    __syncthreads();
  }
  float* pb = preact + (size_t)ks * kB * kH;
#pragma unroll
  for (int r = 0; r < 4; ++r) {
    int row = wave * 16 + kg4 * 4 + r;
    if (row < M) {
      float* pr = pb + (size_t)rows[row] * kH + m15;
#pragma unroll
      for (int nt = 0; nt < 8; ++nt) pr[nt * 16] = acc[nt][r];
    }
  }
}

// Per-token tail: sum k-split slices, bias+relu, w2 matmul, scale, log_softmax.
__global__ __launch_bounds__(64) void expert_tail(
    const float* __restrict__ preact, const float* __restrict__ b1,
    const float* __restrict__ w2, const float* __restrict__ b2,
    const int* __restrict__ idx, const float* __restrict__ scale,
    float* __restrict__ out) {
  const int b = blockIdx.x;
  const int lane = threadIdx.x;
  const int e = idx[b];
  float pa = 0.f, pc = 0.f;
#pragma unroll
  for (int ks = 0; ks < KSPLIT; ++ks) {
    const float* ps = preact + ((size_t)ks * kB + b) * kH;
    pa += ps[lane];
    pc += ps[64 + lane];
  }
  float hea = fmaxf(pa + b1[e * kH + lane], 0.f);
  float heb = fmaxf(pc + b1[e * kH + 64 + lane], 0.f);
  const float* w2a = w2 + ((size_t)e * kH + lane) * kO;
  const float* w2b = w2a + 64 * kO;
  float part[kO];
#pragma unroll
  for (int o = 0; o < kO; ++o) part[o] = hea * w2a[o] + heb * w2b[o];
#pragma unroll
  for (int off = 32; off > 0; off >>= 1)
#pragma unroll
    for (int o = 0; o < kO; ++o) part[o] += __shfl_down(part[o], off, 64);
  if (lane == 0) {
    const float sc = scale[b];
    float v[kO], m = -1e30f;
#pragma unroll
    for (int o = 0; o < kO; ++o) {
      v[o] = (part[o] + b2[e * kO + o]) * sc;
      m = fmaxf(m, v[o]);
    }
    float s = 0.f;
#pragma unroll
    for (int o = 0; o < kO; ++o) s += expf(v[o] - m);
    const float lse = m + logf(s);
#pragma unroll
    for (int o = 0; o < kO; ++o) out[(size_t)b * kO + o] = v[o] - lse;
  }
}

}  // namespace

extern "C" void kernel_launch(void* const* d_in, const int* in_sizes, int n_in,
                              void* d_out, int out_size, void* d_ws,
                              size_t ws_size, hipStream_t stream) {
  (void)in_sizes; (void)n_in; (void)out_size; (void)ws_size;
  const float* x   = (const float*)d_in[0];
  const float* c1w = (const float*)d_in[1];
  const float* c1b = (const float*)d_in[2];
  const float* c2w = (const float*)d_in[3];
  const float* c2b = (const float*)d_in[4];
  const float* gw  = (const float*)d_in[5];
  const float* w1  = (const float*)d_in[6];
  const float* b1  = (const float*)d_in[7];
  const float* w2  = (const float*)d_in[8];
  const float* b2  = (const float*)d_in[9];
  float* out = (float*)d_out;

  char* ws = (char*)d_ws;
  float* h = (float*)ws;
  size_t off = (size_t)kB * kD * sizeof(float);                     // 151.0 MB
  ushort* w1ph = (ushort*)(ws + off); off += (size_t)kE * kD * kH * 2;  // 18.9 MB
  ushort* w1pl = (ushort*)(ws + off); off += (size_t)kE * kD * kH * 2;  // 18.9 MB
  float* preact = (float*)(ws + off); off += (size_t)KSPLIT * kB * kH * 4;  // 16.8 MB
  ushort* Bph = (ushort*)(ws + off);  off += 9 * 4 * 64 * 8 * 2;
  ushort* Bpl = (ushort*)(ws + off);  off += 9 * 4 * 64 * 8 * 2;
  int* idx = (int*)(ws + off);        off += (size_t)kB * 4;
  float* scale = (float*)(ws + off);  off += (size_t)kB * 4;
  int* perm = (int*)(ws + off);       off += (size_t)kB * 4;
  int* counts = (int*)(ws + off);     off += 64;
  int* offsets = (int*)(ws + off);    off += 64;

  prep_w1<<<4608, 256, 0, stream>>>(w1, w1ph, w1pl, c2w, Bph, Bpl, counts);
  conv_kernel<<<kB, 256, 0, stream>>>(x, c1w, c1b, c2b, Bph, Bpl, h);
  gate_kernel<<<kB / 4, 256, 0, stream>>>(h, gw, idx, scale, counts);
  scan_scatter<<<1, 256, 0, stream>>>(counts, idx, offsets, perm);
  dim3 eg(kE, KSPLIT, 16);
  expert_gemm<<<eg, 256, 0, stream>>>(h, w1ph, w1pl, perm, offsets, preact);
  expert_tail<<<kB, 64, 0, stream>>>(preact, b1, w2, b2, idx, scale, out);
}

// Round 4
// 541.041 us; speedup vs baseline: 1.0782x; 1.0446x over previous
//
#include <hip/hip_runtime.h>
#include <math.h>

namespace {
constexpr int kB = 4096;
constexpr int kD = 9216;   // 64*12*12
constexpr int kE = 8;
constexpr int kH = 128;
constexpr int kO = 10;
constexpr int PSTR = 32;   // shorts per h1 pixel (64 B stride)
constexpr int KSPLIT = 8;  // expert GEMM k-split: 9216/8 = 1152

typedef __attribute__((ext_vector_type(8))) short short8;   // 8 bf16
typedef __attribute__((ext_vector_type(4))) float f32x4;    // MFMA acc
typedef __attribute__((ext_vector_type(4))) unsigned u32x4;

__device__ inline unsigned f2bf(float f) {  // fp32 -> bf16 bits, RNE
  unsigned u = __float_as_uint(f);
  return (u + 0x7fffu + ((u >> 16) & 1u)) >> 16;
}
__device__ inline float bf2f(unsigned b) { return __uint_as_float(b << 16); }

// R14: HW packed bf16 convert. v_cvt_pk_bf16_f32 is RNE on gfx950 ->
// bit-identical to f2bf for finite inputs (all our inputs are finite,
// lo-residuals ~2^-9..2^-17 x O(1), far above f32 denormal range).
// D[15:0]=bf16(a), D[31:16]=bf16(b) == the packed word layout we store.
__device__ inline unsigned cvtpk(float a, float b) {
  unsigned d;
  asm("v_cvt_pk_bf16_f32 %0, %1, %2" : "=v"(d) : "v"(a), "v"(b));
  return d;
}
// hi/lo split of a pair in 6 VALU (was ~24 with bit-twiddle f2bf):
// hp = packed hi bf16s; lp = packed lo bf16s (residuals).
__device__ inline void hilo_pair(float a, float b, unsigned& hp, unsigned& lp) {
  hp = cvtpk(a, b);
  float ra = a - __uint_as_float(hp << 16);
  float rb = b - __uint_as_float(hp & 0xffff0000u);
  lp = cvtpk(ra, rb);
}

// w1 -> MFMA B-frag order, bf16 hi/lo. Layout:
// [e][k>>5][nt][lane][j], lane = ((k>>3)&3)<<4 | (n&15), j = k&7.
// Block 0 additionally packs c2w B-frags and zeroes counts.
__global__ __launch_bounds__(256) void prep_w1(
    const float* __restrict__ w1, ushort* __restrict__ w1ph,
    ushort* __restrict__ w1pl, const float* __restrict__ c2w,
    ushort* __restrict__ Bph, ushort* __restrict__ Bpl,
    int* __restrict__ counts) {
  if (blockIdx.x == 0) {
    if (threadIdx.x < kE) counts[threadIdx.x] = 0;
    for (int i = threadIdx.x; i < 9 * 4 * 64 * 8; i += 256) {
      int j = i & 7, lane = (i >> 3) & 63, nt = (i >> 9) & 3, tap = i >> 11;
      int n = nt * 16 + (lane & 15);
      int c1 = (lane >> 4) * 8 + j;
      float v = c2w[(n * 32 + c1) * 9 + tap];
      unsigned hb = f2bf(v);
      Bph[i] = (ushort)hb;
      Bpl[i] = (ushort)f2bf(v - bf2f(hb));
    }
  }
  int t = blockIdx.x * 256 + threadIdx.x;
  int n = t & 127;
  int rem = t >> 7;
  int k8 = rem % 1152;
  int e = rem / 1152;
  const float* src = w1 + ((size_t)e * kD + (size_t)k8 * 8) * kH + n;
  float v[8];
#pragma unroll
  for (int j = 0; j < 8; ++j) v[j] = src[(size_t)j * kH];
  u32x4 hw, lw;
#pragma unroll
  for (int j = 0; j < 4; ++j) {
    unsigned hp, lp;
    hilo_pair(v[2 * j], v[2 * j + 1], hp, lp);
    hw[j] = hp;
    lw[j] = lp;
  }
  size_t base =
      ((((size_t)e * 288 + (k8 >> 2)) * 8 + (n >> 4)) * 64 +
       (((k8 & 3) << 4) | (n & 15))) * 8;
  *(u32x4*)(w1ph + base) = hw;
  *(u32x4*)(w1pl + base) = lw;
}

// One 256-thread block per sample. Wave w owns ntile w (16 chans), covers all
// 18 mt tiles. R11-R13 post-mortems: NOT conflict-bound (counter invariant,
// tracks ds_read count), NOT occupancy-bound (R12: 4 blk/CU slower), NOT
// LDS-read-traffic-bound (R13: halved reads, slower). Model that fits all
// data: ISSUE-bound — MFMA demand ~302k cy/CU (48%) + VALU demand ~280k
// (44%) sum to ~92% of the 634k-cy kernel. R14 attacks the VALU term: the
// software f2bf hi/lo conversion (~24 inst/item, ~40% of conv1 VALU) ->
// v_cvt_pk_bf16_f32 (6 inst/item, bit-identical RNE). NUMERICS FROZEN:
// conv1 FMA order, tap order, Al*Bh -> Ah*Bl -> Ah*Bh chain unchanged;
// conversion results bit-identical (RNE == f2bf on finite values).
__global__ __launch_bounds__(256, 2) void conv_kernel(
    const float* __restrict__ x, const float* __restrict__ c1w,
    const float* __restrict__ c1b, const float* __restrict__ b2g,
    const ushort* __restrict__ Bph, const ushort* __restrict__ Bpl,
    float* __restrict__ h) {
  __shared__ float xs[784];
  __shared__ float w1s[288];
  __shared__ float b1s[32];
  __shared__ ushort h1h[364 * PSTR];  // 23.3 KB
  __shared__ ushort h1l[364 * PSTR];
  const int b = blockIdx.x, tid = threadIdx.x;
  const int lane = tid & 63, wave = tid >> 6;  // wave = ntile (16 chans)

  short8 Bh[9], Bl[9];
#pragma unroll
  for (int tap = 0; tap < 9; ++tap) {
    int fi = ((tap * 4 + wave) * 64 + lane) * 8;
    Bh[tap] = *(const short8*)(Bph + fi);
    Bl[tap] = *(const short8*)(Bpl + fi);
  }
  float b2v = b2g[wave * 16 + (lane & 15)];

  const float* xb = x + (size_t)b * 784;
  for (int i = tid; i < 784; i += 256) xs[i] = xb[i];
  for (int i = tid; i < 288; i += 256) w1s[i] = c1w[i];
  if (tid < 32) b1s[tid] = c1b[tid];
  __syncthreads();

  float* hb = h + (size_t)b * kD;
  for (int pass = 0; pass < 2; ++pass) {
    for (int i = tid; i < 364 * 16; i += 256) {
      int p = i >> 4, cp = (i & 15) * 2;
      int r = p / 26, col = p - r * 26;
      const float* xr = xs + (pass * 12 + r) * 28 + col;
      const float* w0 = w1s + cp * 9;
      float v0 = b1s[cp], v1 = b1s[cp + 1];
#pragma unroll
      for (int ky = 0; ky < 3; ++ky)
#pragma unroll
        for (int kx = 0; kx < 3; ++kx) {
          float xv = xr[ky * 28 + kx];
          v0 += xv * w0[ky * 3 + kx];
          v1 += xv * w0[9 + ky * 3 + kx];
        }
      v0 = fmaxf(v0, 0.f);
      v1 = fmaxf(v1, 0.f);
      unsigned hp, lp;
      hilo_pair(v0, v1, hp, lp);  // bit-identical to f2bf path (RNE)
      *(unsigned*)&h1h[p * PSTR + cp] = hp;
      *(unsigned*)&h1l[p * PSTR + cp] = lp;
    }
    __syncthreads();
    const int m = lane & 15, kg = lane >> 4;
    for (int mt = 0; mt < 18; ++mt) {
      int cell = mt * 4 + (m >> 2), sub = m & 3;
      int cy = cell / 12, cx = cell - cy * 12;
      int yy = 2 * cy + (sub >> 1), xx = 2 * cx + (sub & 1);
      const ushort* ah = h1h + (yy * 26 + xx) * PSTR + kg * 8;
      const ushort* al = h1l + (yy * 26 + xx) * PSTR + kg * 8;
      f32x4 acc = {0.f, 0.f, 0.f, 0.f};
#pragma unroll
      for (int ky = 0; ky < 3; ++ky)
#pragma unroll
        for (int kx = 0; kx < 3; ++kx) {
          const int tap = ky * 3 + kx;
          short8 Ah = *(const short8*)(ah + (ky * 26 + kx) * PSTR);  // b128
          short8 Al = *(const short8*)(al + (ky * 26 + kx) * PSTR);
          acc = __builtin_amdgcn_mfma_f32_16x16x32_bf16(Al, Bh[tap], acc, 0, 0, 0);
          acc = __builtin_amdgcn_mfma_f32_16x16x32_bf16(Ah, Bl[tap], acc, 0, 0, 0);
          acc = __builtin_amdgcn_mfma_f32_16x16x32_bf16(Ah, Bh[tap], acc, 0, 0, 0);
        }
      int cellg = mt * 4 + kg;
      int gy = cellg / 12, gx = cellg - gy * 12;
      int orow = (pass * 6 + gy) * 12 + gx;
      float p0 = fmaxf(fmaxf(acc[0], acc[1]), fmaxf(acc[2], acc[3]));
      hb[(wave * 16 + m) * 144 + orow] = fmaxf(p0 + b2v, 0.f);
    }
    __syncthreads();
  }
}

// 4 tokens per 256-thread block; per-wave numerics frozen (R5 verbatim).
__global__ __launch_bounds__(256) void gate_kernel(
    const float* __restrict__ h, const float* __restrict__ gw,
    int* __restrict__ idx, float* __restrict__ scale,
    int* __restrict__ counts) {
  const int b = blockIdx.x * 4 + (threadIdx.x >> 6);
  const int lane = threadIdx.x & 63;
  const float* hb = h + (size_t)b * kD;
  float acc[kE] = {0, 0, 0, 0, 0, 0, 0, 0};
  for (int i = lane; i < kD; i += 64) {
    float hv = hb[i];
    const float* g = gw + (size_t)i * kE;
#pragma unroll
    for (int e = 0; e < kE; ++e) acc[e] += hv * g[e];
  }
#pragma unroll
  for (int off = 32; off > 0; off >>= 1) {
#pragma unroll
    for (int e = 0; e < kE; ++e) acc[e] += __shfl_down(acc[e], off, 64);
  }
  if (lane == 0) {
    float m = acc[0];
    int bi = 0;
#pragma unroll
    for (int e = 1; e < kE; ++e)
      if (acc[e] > m) { m = acc[e]; bi = e; }
    float s = 0.f;
#pragma unroll
    for (int e = 0; e < kE; ++e) s += expf(acc[e] - m);
    idx[b] = bi;
    scale[b] = 1.0f / s;
    atomicAdd(&counts[bi], 1);
  }
}

// Single block: exclusive scan of counts + bucket scatter via LDS cursors.
__global__ __launch_bounds__(256) void scan_scatter(
    const int* __restrict__ counts, const int* __restrict__ idx,
    int* __restrict__ offsets, int* __restrict__ perm) {
  __shared__ int soff[kE + 1];
  __shared__ int cur[kE];
  if (threadIdx.x == 0) {
    int o = 0;
    for (int e = 0; e < kE; ++e) {
      soff[e] = o;
      cur[e] = o;
      o += counts[e];
    }
    soff[kE] = o;
  }
  __syncthreads();
  for (int b = threadIdx.x; b < kB; b += 256) {
    int e = idx[b];
    int pos = atomicAdd(&cur[e], 1);
    perm[pos] = b;
  }
  if (threadIdx.x <= kE) offsets[threadIdx.x] = soff[threadIdx.x];
}

// MFMA expert GEMM. Grid (e=8, ks=8, tile=16). B staged through LDS once per
// block per bk (R9 win). R14: stage-A conversion via cvt_pk (bit-identical).
__global__ __launch_bounds__(256) void expert_gemm(
    const float* __restrict__ h, const ushort* __restrict__ w1ph,
    const ushort* __restrict__ w1pl, const int* __restrict__ perm,
    const int* __restrict__ offsets, float* __restrict__ preact) {
  const int e = blockIdx.x, ks = blockIdx.y;
  const int start = offsets[e] + blockIdx.z * 64;
  const int end = offsets[e + 1];
  if (start >= end) return;
  const int M = min(64, end - start);
  __shared__ ushort Afh[4096];  // A frags [kstep][g][lane][8], 8 KB
  __shared__ ushort Afl[4096];
  __shared__ ushort Bsh[8192];  // B frags [kstep][nt][lane][8], 16 KB
  __shared__ ushort Bsl[8192];
  __shared__ int rows[64];
  const int tid = threadIdx.x;
  if (tid < 64) rows[tid] = perm[start + min(tid, M - 1)];
  __syncthreads();
  const int wave = tid >> 6, lane = tid & 63;
  const int m15 = lane & 15, kg4 = lane >> 4;
  const int srow = tid >> 2, spart = tid & 3;
  const int kbase = ks * (kD / KSPLIT);
  const float* hp0 = h + (size_t)rows[srow] * kD + kbase + spart * 16;
  const int skstep = spart >> 1, skg = (spart & 1) * 2;
  const int sg = srow >> 4, sm = srow & 15;
  ushort* wh0 = &Afh[((skstep * 4 + sg) * 64 + skg * 16 + sm) * 8];
  ushort* wl0 = &Afl[((skstep * 4 + sg) * 64 + skg * 16 + sm) * 8];
  f32x4 acc[8];
#pragma unroll
  for (int j = 0; j < 8; ++j) acc[j] = {0.f, 0.f, 0.f, 0.f};

  for (int bk = 0; bk < kD / KSPLIT; bk += 64) {
    // ---- stage A (cvt_pk hi/lo, bit-identical to f2bf path) ----
#pragma unroll
    for (int c = 0; c < 2; ++c) {
      float4 v0 = *(const float4*)(hp0 + bk + c * 8);
      float4 v1 = *(const float4*)(hp0 + bk + c * 8 + 4);
      float f[8] = {v0.x, v0.y, v0.z, v0.w, v1.x, v1.y, v1.z, v1.w};
      u32x4 hw, lw;
#pragma unroll
      for (int j = 0; j < 4; ++j) {
        unsigned hp, lp;
        hilo_pair(f[2 * j], f[2 * j + 1], hp, lp);
        hw[j] = hp;
        lw[j] = lp;
      }
      *(u32x4*)(wh0 + c * 128) = hw;
      *(u32x4*)(wl0 + c * 128) = lw;
    }
    // ---- stage B: 2 kg32 blocks x 4096 shorts, contiguous in w1p ----
    {
      const size_t bbase =
          ((size_t)e * 288 + ((kbase + bk) >> 5)) * 4096;
#pragma unroll
      for (int q = 0; q < 4; ++q) {
        int c = tid + q * 256;  // b128 chunk id, 1024 total
        *(short8*)&Bsh[c * 8] = *(const short8*)(w1ph + bbase + (size_t)c * 8);
        *(short8*)&Bsl[c * 8] = *(const short8*)(w1pl + bbase + (size_t)c * 8);
      }
    }
    __syncthreads();
#pragma unroll
    for (int kstep = 0; kstep < 2; ++kstep) {
      const ushort* af = &Afh[((kstep * 4 + wave) * 64 + lane) * 8];
      short8 ah = *(const short8*)af;
      short8 al = *(const short8*)(af + (Afl - Afh));
      const ushort* bph = &Bsh[kstep * 4096 + lane * 8];
      const ushort* bpl = &Bsl[kstep * 4096 + lane * 8];
#pragma unroll
      for (int nt = 0; nt < 8; ++nt) {
        short8 bh = *(const short8*)(bph + nt * 512);
        short8 bl = *(const short8*)(bpl + nt * 512);
        acc[nt] = __builtin_amdgcn_mfma_f32_16x16x32_bf16(al, bh, acc[nt], 0, 0, 0);
        acc[nt] = __builtin_amdgcn_mfma_f32_16x16x32_bf16(ah, bl, acc[nt], 0, 0, 0);
        acc[nt] = __builtin_amdgcn_mfma_f32_16x16x32_bf16(ah, bh, acc[nt], 0, 0, 0);
      }
    }
    __syncthreads();
  }
  float* pb = preact + (size_t)ks * kB * kH;
#pragma unroll
  for (int r = 0; r < 4; ++r) {
    int row = wave * 16 + kg4 * 4 + r;
    if (row < M) {
      float* pr = pb + (size_t)rows[row] * kH + m15;
#pragma unroll
      for (int nt = 0; nt < 8; ++nt) pr[nt * 16] = acc[nt][r];
    }
  }
}

// Per-token tail: sum k-split slices, bias+relu, w2 matmul, scale, log_softmax.
__global__ __launch_bounds__(64) void expert_tail(
    const float* __restrict__ preact, const float* __restrict__ b1,
    const float* __restrict__ w2, const float* __restrict__ b2,
    const int* __restrict__ idx, const float* __restrict__ scale,
    float* __restrict__ out) {
  const int b = blockIdx.x;
  const int lane = threadIdx.x;
  const int e = idx[b];
  float pa = 0.f, pc = 0.f;
#pragma unroll
  for (int ks = 0; ks < KSPLIT; ++ks) {
    const float* ps = preact + ((size_t)ks * kB + b) * kH;
    pa += ps[lane];
    pc += ps[64 + lane];
  }
  float hea = fmaxf(pa + b1[e * kH + lane], 0.f);
  float heb = fmaxf(pc + b1[e * kH + 64 + lane], 0.f);
  const float* w2a = w2 + ((size_t)e * kH + lane) * kO;
  const float* w2b = w2a + 64 * kO;
  float part[kO];
#pragma unroll
  for (int o = 0; o < kO; ++o) part[o] = hea * w2a[o] + heb * w2b[o];
#pragma unroll
  for (int off = 32; off > 0; off >>= 1)
#pragma unroll
    for (int o = 0; o < kO; ++o) part[o] += __shfl_down(part[o], off, 64);
  if (lane == 0) {
    const float sc = scale[b];
    float v[kO], m = -1e30f;
#pragma unroll
    for (int o = 0; o < kO; ++o) {
      v[o] = (part[o] + b2[e * kO + o]) * sc;
      m = fmaxf(m, v[o]);
    }
    float s = 0.f;
#pragma unroll
    for (int o = 0; o < kO; ++o) s += expf(v[o] - m);
    const float lse = m + logf(s);
#pragma unroll
    for (int o = 0; o < kO; ++o) out[(size_t)b * kO + o] = v[o] - lse;
  }
}

}  // namespace

extern "C" void kernel_launch(void* const* d_in, const int* in_sizes, int n_in,
                              void* d_out, int out_size, void* d_ws,
                              size_t ws_size, hipStream_t stream) {
  (void)in_sizes; (void)n_in; (void)out_size; (void)ws_size;
  const float* x   = (const float*)d_in[0];
  const float* c1w = (const float*)d_in[1];
  const float* c1b = (const float*)d_in[2];
  const float* c2w = (const float*)d_in[3];
  const float* c2b = (const float*)d_in[4];
  const float* gw  = (const float*)d_in[5];
  const float* w1  = (const float*)d_in[6];
  const float* b1  = (const float*)d_in[7];
  const float* w2  = (const float*)d_in[8];
  const float* b2  = (const float*)d_in[9];
  float* out = (float*)d_out;

  char* ws = (char*)d_ws;
  float* h = (float*)ws;
  size_t off = (size_t)kB * kD * sizeof(float);                     // 151.0 MB
  ushort* w1ph = (ushort*)(ws + off); off += (size_t)kE * kD * kH * 2;  // 18.9 MB
  ushort* w1pl = (ushort*)(ws + off); off += (size_t)kE * kD * kH * 2;  // 18.9 MB
  float* preact = (float*)(ws + off); off += (size_t)KSPLIT * kB * kH * 4;  // 16.8 MB
  ushort* Bph = (ushort*)(ws + off);  off += 9 * 4 * 64 * 8 * 2;
  ushort* Bpl = (ushort*)(ws + off);  off += 9 * 4 * 64 * 8 * 2;
  int* idx = (int*)(ws + off);        off += (size_t)kB * 4;
  float* scale = (float*)(ws + off);  off += (size_t)kB * 4;
  int* perm = (int*)(ws + off);       off += (size_t)kB * 4;
  int* counts = (int*)(ws + off);     off += 64;
  int* offsets = (int*)(ws + off);    off += 64;

  prep_w1<<<4608, 256, 0, stream>>>(w1, w1ph, w1pl, c2w, Bph, Bpl, counts);
  conv_kernel<<<kB, 256, 0, stream>>>(x, c1w, c1b, c2b, Bph, Bpl, h);
  gate_kernel<<<kB / 4, 256, 0, stream>>>(h, gw, idx, scale, counts);
  scan_scatter<<<1, 256, 0, stream>>>(counts, idx, offsets, perm);
  dim3 eg(kE, KSPLIT, 16);
  expert_gemm<<<eg, 256, 0, stream>>>(h, w1ph, w1pl, perm, offsets, preact);
  expert_tail<<<kB, 64, 0, stream>>>(preact, b1, w2, b2, idx, scale, out);
}